// Round 1
// baseline (104.436 us; speedup 1.0000x reference)
//
#include <hip/hip_runtime.h>
#include <hip/hip_bf16.h>
#include <stdint.h>

typedef __attribute__((ext_vector_type(8))) short bf16x8;
typedef __attribute__((ext_vector_type(4))) float f32x4;

#define NN 1024     // nodes
#define KD 512      // 2*LDIMS
#define NC 256      // 2*HID
#define H2 64       // HID2

// ws layout (bytes)
#define OFF_A    0            // A bf16 [1024][512]  = 1,048,576
#define OFF_WT   1048576      // Wt bf16 [256][512]  =   262,144
#define OFF_WHB  1310720      // Whb bf16 [64][256]  =    32,768
#define OFF_G    1343488      // g bf16  [1024][256] =   524,288
#define OFF_PT   1867776      // Pt f32  [64][1024]  =   262,144
#define OFF_QT   2129920      // Qt f32  [64][1024]  =   262,144
// total: 2,392,064 + 262,144 = 2,654,208 bytes

#define TANH_SCALE 2.8853900817779268f   // 2*log2(e)

static __device__ __forceinline__ ushort f2bf(float f) {
    uint32_t u = __builtin_bit_cast(uint32_t, f);
    uint32_t r = (u + 0x7fffu + ((u >> 16) & 1u)) >> 16;
    return (ushort)r;
}

// ---------------- K0: pack/convert/transpose ----------------
__global__ __launch_bounds__(256) void k0_pack(const float* __restrict__ x,
                                               const float* __restrict__ W_foh,
                                               const float* __restrict__ W_fom,
                                               const float* __restrict__ W_hid2,
                                               ushort* __restrict__ A,
                                               ushort* __restrict__ Wt,
                                               ushort* __restrict__ Whb) {
    int tid = blockIdx.x * 256 + threadIdx.x;
    if (tid < 131072) {
        // A: x [1024][512] f32 -> bf16, 4 elems/thread
        float4 v = ((const float4*)x)[tid];
        ushort4 o;
        o.x = f2bf(v.x); o.y = f2bf(v.y); o.z = f2bf(v.z); o.w = f2bf(v.w);
        ((ushort4*)A)[tid] = o;
    } else if (tid < 262144) {
        // Wt[c][k] = (c<128 ? W_foh[k][c] : W_fom[k][c-128]), bf16
        int t2 = tid - 131072;
        int c = t2 & 255, k = t2 >> 8;
        float v = (c < 128) ? W_foh[k * 128 + c] : W_fom[k * 128 + c - 128];
        Wt[c * 512 + k] = f2bf(v);
    } else if (tid < 278528) {
        // Whb[d][c] = W_hid2[c][d], bf16
        int t3 = tid - 262144;
        int d = t3 & 63, c = t3 >> 6;
        Whb[d * 256 + c] = f2bf(W_hid2[c * 64 + d]);
    }
}

// ---------------- K1: g = tanh(xf @ Wcat + cat_bias), bf16 out ----------------
// 256 blocks x 256 thr; wave = one 16x16 output tile; direct-from-global frags.
__global__ __launch_bounds__(256) void k1_gemm1(const ushort* __restrict__ A,
                                                const ushort* __restrict__ Wt,
                                                const float* __restrict__ cat_bias,
                                                ushort* __restrict__ g) {
    int lane = threadIdx.x & 63;
    int wave = threadIdx.x >> 6;
    int b = blockIdx.x;
    int ntile = b & 15;                  // 16 n-tiles (256 cols)
    int mtile = (b >> 4) * 4 + wave;     // 64 m-tiles; waves share ntile -> B frags L1-hit
    int l15 = lane & 15;
    int kofs = (lane >> 4) * 8;
    const ushort* Ar = A + (mtile * 16 + l15) * 512 + kofs;
    const ushort* Br = Wt + (ntile * 16 + l15) * 512 + kofs;
    f32x4 acc = {0.f, 0.f, 0.f, 0.f};
#pragma unroll
    for (int s = 0; s < 16; ++s) {
        bf16x8 a = *(const bf16x8*)(Ar + s * 32);
        bf16x8 bb = *(const bf16x8*)(Br + s * 32);
        acc = __builtin_amdgcn_mfma_f32_16x16x32_bf16(a, bb, acc, 0, 0, 0);
    }
    int col = ntile * 16 + l15;
    float cb = cat_bias[col];
#pragma unroll
    for (int r = 0; r < 4; ++r) {
        int row = mtile * 16 + (lane >> 4) * 4 + r;
        float xv = acc[r] + cb;
        float e = exp2f(xv * TANH_SCALE);
        float t = 1.0f - 2.0f * __builtin_amdgcn_rcpf(e + 1.0f);
        g[row * 256 + col] = f2bf(t);
    }
}

// ---------------- K2: P/Q = (g @ W_hid2 halves [+bias]) * scale, transposed f32 ----------------
// 128 blocks x 256 thr = 512 waves: (half, mtile 0..63, dtile 0..3)
__global__ __launch_bounds__(256) void k2_gemm2(const ushort* __restrict__ g,
                                                const ushort* __restrict__ Whb,
                                                const float* __restrict__ hid2_bias,
                                                float* __restrict__ Pt,
                                                float* __restrict__ Qt) {
    int lane = threadIdx.x & 63;
    int wv = blockIdx.x * 4 + (threadIdx.x >> 6);   // 0..511
    int mtile = wv & 63;
    int dtile = (wv >> 6) & 3;
    int half = wv >> 8;
    int cbase = half * 128;
    int l15 = lane & 15;
    int kofs = (lane >> 4) * 8;
    const ushort* Ar = g + (mtile * 16 + l15) * 256 + cbase + kofs;
    const ushort* Br = Whb + (dtile * 16 + l15) * 256 + cbase + kofs;
    f32x4 acc = {0.f, 0.f, 0.f, 0.f};
#pragma unroll
    for (int s = 0; s < 4; ++s) {
        bf16x8 a = *(const bf16x8*)(Ar + s * 32);
        bf16x8 bb = *(const bf16x8*)(Br + s * 32);
        acc = __builtin_amdgcn_mfma_f32_16x16x32_bf16(a, bb, acc, 0, 0, 0);
    }
    int dcol = dtile * 16 + l15;
    float* out = half ? Qt : Pt;
    float badd = half ? 0.0f : hid2_bias[dcol];
#pragma unroll
    for (int r = 0; r < 4; ++r) {
        int i = mtile * 16 + (lane >> 4) * 4 + r;
        out[dcol * 1024 + i] = (acc[r] + badd) * TANH_SCALE;
    }
}

// ---------------- K3: scores[i][j] = base + sum_d w'_d / (exp2(P+Q)+1) ----------------
// 256 blocks (16x16 tile grid of 64x64), 256 thr, 4x4 per thread.
__global__ __launch_bounds__(256) void k3_scores(const float* __restrict__ Pt,
                                                 const float* __restrict__ Qt,
                                                 const float* __restrict__ W_out,
                                                 const float* __restrict__ out_bias,
                                                 float* __restrict__ out) {
    __shared__ float Pl[64][68];   // +4 pad: write conflicts 4-way, read 2-way (free)
    __shared__ float Ql[64][68];
    __shared__ float wl[64];
    int t = threadIdx.x;
    int b = blockIdx.x;
    int i0 = (b >> 4) * 64;
    int j0 = (b & 15) * 64;
    {
        int rowd = t >> 2;              // 0..63  (coalesced global reads)
        int cch = (t & 3) * 16;         // 0,16,32,48
        const float4* ps = (const float4*)(Pt + rowd * 1024 + i0 + cch);
        const float4* qs = (const float4*)(Qt + rowd * 1024 + j0 + cch);
#pragma unroll
        for (int u = 0; u < 4; ++u) {
            *(float4*)(&Pl[rowd][cch + u * 4]) = ps[u];
            *(float4*)(&Ql[rowd][cch + u * 4]) = qs[u];
        }
    }
    if (t < 64) wl[t] = -2.0f * W_out[t];
    float base = out_bias[0];
#pragma unroll
    for (int d = 0; d < 64; ++d) base += W_out[d];   // uniform s_loads, cheap
    __syncthreads();

    int il = (t & 15) * 4;
    int jl = (t >> 4) * 4;
    float acc[4][4] = {};
#pragma unroll 4
    for (int d = 0; d < 64; ++d) {
        f32x4 p = *(const f32x4*)(&Pl[d][il]);
        f32x4 q = *(const f32x4*)(&Ql[d][jl]);
        float w = wl[d];
#pragma unroll
        for (int a = 0; a < 4; ++a)
#pragma unroll
            for (int c = 0; c < 4; ++c) {
                float e = exp2f(p[a] + q[c]);
                float r = __builtin_amdgcn_rcpf(e + 1.0f);
                acc[a][c] = fmaf(w, r, acc[a][c]);
            }
    }
#pragma unroll
    for (int a = 0; a < 4; ++a) {
        float4 v;
        v.x = base + acc[a][0];
        v.y = base + acc[a][1];
        v.z = base + acc[a][2];
        v.w = base + acc[a][3];
        *(float4*)(&out[(i0 + il + a) * 1024 + j0 + jl]) = v;
    }
}

extern "C" void kernel_launch(void* const* d_in, const int* in_sizes, int n_in,
                              void* d_out, int out_size, void* d_ws, size_t ws_size,
                              hipStream_t stream) {
    const float* x        = (const float*)d_in[0];
    const float* W_foh    = (const float*)d_in[1];
    const float* W_fom    = (const float*)d_in[2];
    const float* cat_bias = (const float*)d_in[3];
    const float* W_hid2   = (const float*)d_in[4];
    const float* hid2_bias= (const float*)d_in[5];
    const float* W_out    = (const float*)d_in[6];
    const float* out_bias = (const float*)d_in[7];

    char* ws = (char*)d_ws;
    ushort* A   = (ushort*)(ws + OFF_A);
    ushort* Wt  = (ushort*)(ws + OFF_WT);
    ushort* Whb = (ushort*)(ws + OFF_WHB);
    ushort* g   = (ushort*)(ws + OFF_G);
    float*  Pt  = (float*)(ws + OFF_PT);
    float*  Qt  = (float*)(ws + OFF_QT);

    k0_pack<<<1088, 256, 0, stream>>>(x, W_foh, W_fom, W_hid2, A, Wt, Whb);
    k1_gemm1<<<256, 256, 0, stream>>>(A, Wt, cat_bias, g);
    k2_gemm2<<<128, 256, 0, stream>>>(g, Whb, hid2_bias, Pt, Qt);
    k3_scores<<<256, 256, 0, stream>>>(Pt, Qt, W_out, out_bias, (float*)d_out);
}

// Round 2
// 103.934 us; speedup vs baseline: 1.0048x; 1.0048x over previous
//
#include <hip/hip_runtime.h>
#include <hip/hip_bf16.h>
#include <stdint.h>

typedef __attribute__((ext_vector_type(8))) short bf16x8;
typedef __attribute__((ext_vector_type(4))) float f32x4;

#define NN 1024     // nodes
#define KD 512      // 2*LDIMS
#define NC 256      // 2*HID
#define H2 64       // HID2

// ws layout (bytes)
#define OFF_A    0            // A bf16 [1024][512]  = 1,048,576
#define OFF_WT   1048576      // Wt bf16 [256][512]  =   262,144
#define OFF_WHB  1310720      // Whb bf16 [64][256]  =    32,768
#define OFF_G    1343488      // g bf16  [1024][256] =   524,288
#define OFF_PT   1867776      // Pt f32  [64][1024]  =   262,144
#define OFF_QT   2129920      // Qt f32  [64][1024]  =   262,144

#define TANH_SCALE 2.8853900817779268f   // 2*log2(e)

static __device__ __forceinline__ ushort f2bf(float f) {
    uint32_t u = __builtin_bit_cast(uint32_t, f);
    uint32_t r = (u + 0x7fffu + ((u >> 16) & 1u)) >> 16;
    return (ushort)r;
}

// ---------------- K0: pack/convert/transpose ----------------
__global__ __launch_bounds__(256) void k0_pack(const float* __restrict__ x,
                                               const float* __restrict__ W_foh,
                                               const float* __restrict__ W_fom,
                                               const float* __restrict__ W_hid2,
                                               ushort* __restrict__ A,
                                               ushort* __restrict__ Wt,
                                               ushort* __restrict__ Whb) {
    int tid = blockIdx.x * 256 + threadIdx.x;
    if (tid < 131072) {
        float4 v = ((const float4*)x)[tid];
        ushort4 o;
        o.x = f2bf(v.x); o.y = f2bf(v.y); o.z = f2bf(v.z); o.w = f2bf(v.w);
        ((ushort4*)A)[tid] = o;
    } else if (tid < 262144) {
        int t2 = tid - 131072;
        int c = t2 & 255, k = t2 >> 8;
        float v = (c < 128) ? W_foh[k * 128 + c] : W_fom[k * 128 + c - 128];
        Wt[c * 512 + k] = f2bf(v);
    } else if (tid < 278528) {
        int t3 = tid - 262144;
        int d = t3 & 63, c = t3 >> 6;
        Whb[d * 256 + c] = f2bf(W_hid2[c * 64 + d]);
    }
}

// ---------------- K1: g = tanh(xf @ Wcat + cat_bias), bf16 out ----------------
// 1024 blocks (one 16x16 tile each); 4 waves split K=512 into 4x128; LDS reduce.
// 4096 waves = 4 waves/SIMD -> latency hidden.
__global__ __launch_bounds__(256) void k1_gemm1(const ushort* __restrict__ A,
                                                const ushort* __restrict__ Wt,
                                                const float* __restrict__ cat_bias,
                                                ushort* __restrict__ g) {
    __shared__ float red[4 * 64 * 4];
    int lane = threadIdx.x & 63;
    int wave = threadIdx.x >> 6;
    int b = blockIdx.x;
    int ntile = b & 15;
    int mtile = b >> 4;
    int l15 = lane & 15;
    int kofs = wave * 128 + (lane >> 4) * 8;
    const ushort* Ar = A + (mtile * 16 + l15) * 512 + kofs;
    const ushort* Br = Wt + (ntile * 16 + l15) * 512 + kofs;
    f32x4 acc = {0.f, 0.f, 0.f, 0.f};
#pragma unroll
    for (int s = 0; s < 4; ++s) {
        bf16x8 a = *(const bf16x8*)(Ar + s * 32);
        bf16x8 bb = *(const bf16x8*)(Br + s * 32);
        acc = __builtin_amdgcn_mfma_f32_16x16x32_bf16(a, bb, acc, 0, 0, 0);
    }
    *(f32x4*)(&red[(wave * 64 + lane) * 4]) = acc;
    __syncthreads();
    if (wave == 0) {
        f32x4 s0 = *(const f32x4*)(&red[(0 * 64 + lane) * 4]);
        f32x4 s1 = *(const f32x4*)(&red[(1 * 64 + lane) * 4]);
        f32x4 s2 = *(const f32x4*)(&red[(2 * 64 + lane) * 4]);
        f32x4 s3 = *(const f32x4*)(&red[(3 * 64 + lane) * 4]);
        int col = ntile * 16 + l15;
        float cb = cat_bias[col];
#pragma unroll
        for (int r = 0; r < 4; ++r) {
            int row = mtile * 16 + (lane >> 4) * 4 + r;
            float xv = s0[r] + s1[r] + s2[r] + s3[r] + cb;
            float e = exp2f(xv * TANH_SCALE);
            float t = 1.0f - 2.0f * __builtin_amdgcn_rcpf(e + 1.0f);
            g[row * 256 + col] = f2bf(t);
        }
    }
}

// ---------------- K2: P/Q = (g @ W_hid2 halves [+bias]) * scale, transposed f32 ----------------
__global__ __launch_bounds__(256) void k2_gemm2(const ushort* __restrict__ g,
                                                const ushort* __restrict__ Whb,
                                                const float* __restrict__ hid2_bias,
                                                float* __restrict__ Pt,
                                                float* __restrict__ Qt) {
    int lane = threadIdx.x & 63;
    int wv = blockIdx.x * 4 + (threadIdx.x >> 6);   // 0..511
    int mtile = wv & 63;
    int dtile = (wv >> 6) & 3;
    int half = wv >> 8;
    int cbase = half * 128;
    int l15 = lane & 15;
    int kofs = (lane >> 4) * 8;
    const ushort* Ar = g + (mtile * 16 + l15) * 256 + cbase + kofs;
    const ushort* Br = Whb + (dtile * 16 + l15) * 256 + cbase + kofs;
    f32x4 acc = {0.f, 0.f, 0.f, 0.f};
#pragma unroll
    for (int s = 0; s < 4; ++s) {
        bf16x8 a = *(const bf16x8*)(Ar + s * 32);
        bf16x8 bb = *(const bf16x8*)(Br + s * 32);
        acc = __builtin_amdgcn_mfma_f32_16x16x32_bf16(a, bb, acc, 0, 0, 0);
    }
    int dcol = dtile * 16 + l15;
    float* out = half ? Qt : Pt;
    float badd = half ? 0.0f : hid2_bias[dcol];
#pragma unroll
    for (int r = 0; r < 4; ++r) {
        int i = mtile * 16 + (lane >> 4) * 4 + r;
        out[dcol * 1024 + i] = (acc[r] + badd) * TANH_SCALE;
    }
}

// ---------------- K3: scores[i][j] = base + sum_d w'_d / (exp2(P+Q)+1) ----------------
// 512 blocks: 16 i-tiles x 32 j-tiles of 64x32. 256 thr, 4(i)x2(j) per thread.
// 2048 waves = 2 waves/SIMD -> trans/LDS stalls cross-hidden.
__global__ __launch_bounds__(256) void k3_scores(const float* __restrict__ Pt,
                                                 const float* __restrict__ Qt,
                                                 const float* __restrict__ W_out,
                                                 const float* __restrict__ out_bias,
                                                 float* __restrict__ out) {
    __shared__ float Pl[64][68];
    __shared__ float Ql[64][36];
    __shared__ float wl[64];
    int t = threadIdx.x;
    int b = blockIdx.x;
    int i0 = (b >> 5) * 64;
    int j0 = (b & 31) * 32;
    {   // P tile: 64 d-rows x 64 i-cols; 16 floats/thread
        int rowd = t >> 2;
        int cch = (t & 3) * 16;
        const float4* ps = (const float4*)(Pt + rowd * 1024 + i0 + cch);
#pragma unroll
        for (int u = 0; u < 4; ++u) *(float4*)(&Pl[rowd][cch + u * 4]) = ps[u];
    }
    {   // Q tile: 64 d-rows x 32 j-cols; 8 floats/thread
        int rowd = t >> 2;
        int cch = (t & 3) * 8;
        const float4* qs = (const float4*)(Qt + rowd * 1024 + j0 + cch);
        *(float4*)(&Ql[rowd][cch]) = qs[0];
        *(float4*)(&Ql[rowd][cch + 4]) = qs[1];
    }
    if (t < 64) wl[t] = -2.0f * W_out[t];
    float base = out_bias[0];
#pragma unroll
    for (int d = 0; d < 64; ++d) base += W_out[d];   // uniform s_loads
    __syncthreads();

    int il = (t & 15) * 4;
    int jl = (t >> 4) * 2;
    float acc[4][2] = {};
#pragma unroll 8
    for (int d = 0; d < 64; ++d) {
        f32x4 p = *(const f32x4*)(&Pl[d][il]);
        float q0 = Ql[d][jl], q1 = Ql[d][jl + 1];
        float w = wl[d];
#pragma unroll
        for (int a = 0; a < 4; ++a) {
            float e0 = exp2f(p[a] + q0);
            float r0 = __builtin_amdgcn_rcpf(e0 + 1.0f);
            acc[a][0] = fmaf(w, r0, acc[a][0]);
            float e1 = exp2f(p[a] + q1);
            float r1 = __builtin_amdgcn_rcpf(e1 + 1.0f);
            acc[a][1] = fmaf(w, r1, acc[a][1]);
        }
    }
#pragma unroll
    for (int a = 0; a < 4; ++a) {
        float2 v;
        v.x = base + acc[a][0];
        v.y = base + acc[a][1];
        *(float2*)(&out[(i0 + il + a) * 1024 + j0 + jl]) = v;
    }
}

extern "C" void kernel_launch(void* const* d_in, const int* in_sizes, int n_in,
                              void* d_out, int out_size, void* d_ws, size_t ws_size,
                              hipStream_t stream) {
    const float* x        = (const float*)d_in[0];
    const float* W_foh    = (const float*)d_in[1];
    const float* W_fom    = (const float*)d_in[2];
    const float* cat_bias = (const float*)d_in[3];
    const float* W_hid2   = (const float*)d_in[4];
    const float* hid2_bias= (const float*)d_in[5];
    const float* W_out    = (const float*)d_in[6];
    const float* out_bias = (const float*)d_in[7];

    char* ws = (char*)d_ws;
    ushort* A   = (ushort*)(ws + OFF_A);
    ushort* Wt  = (ushort*)(ws + OFF_WT);
    ushort* Whb = (ushort*)(ws + OFF_WHB);
    ushort* g   = (ushort*)(ws + OFF_G);
    float*  Pt  = (float*)(ws + OFF_PT);
    float*  Qt  = (float*)(ws + OFF_QT);

    k0_pack<<<1088, 256, 0, stream>>>(x, W_foh, W_fom, W_hid2, A, Wt, Whb);
    k1_gemm1<<<1024, 256, 0, stream>>>(A, Wt, cat_bias, g);
    k2_gemm2<<<128, 256, 0, stream>>>(g, Whb, hid2_bias, Pt, Qt);
    k3_scores<<<512, 256, 0, stream>>>(Pt, Qt, W_out, out_bias, (float*)d_out);
}